// Round 1
// baseline (739.561 us; speedup 1.0000x reference)
//
#include <hip/hip_runtime.h>

// Problem constants (match reference)
constexpr int K    = 27;
constexpr int CIN  = 16;
constexpr int COUT = 4;
constexpr int NS   = 3;
constexpr int WSZ  = K * CIN * COUT;   // 1728 floats per stencil
// +8 floats pad per stencil: stride 1736 ≡ 8 (mod 32 banks) -> the 3 per-lane
// stencil variants hit disjoint bank groups on ds_read_b128 (no 3-way conflict).
// 1736*4 bytes stays 16B-aligned so float4 LDS reads remain legal.
constexpr int WPAD = WSZ + 8;

__global__ __launch_bounds__(256) void outblock_kernel(
    const float* __restrict__ x,     // [N, 16]
    const float* __restrict__ W,     // [3, 27, 16, 4]
    const int*   __restrict__ aprs,  // [N, 27]
    const int*   __restrict__ lvl,   // [N]
    float*       __restrict__ out,   // [N, 4]
    int n)
{
    __shared__ float Wl[NS * WPAD];
    // Cooperative stage of all 3 stencils into LDS (5184 floats, ~20.7 KB padded)
    for (int i = threadIdx.x; i < NS * WSZ; i += 256) {
        int s = i / WSZ;
        int r = i - s * WSZ;
        Wl[s * WPAD + r] = W[i];
    }
    __syncthreads();

    int nIdx = blockIdx.x * 256 + threadIdx.x;
    if (nIdx >= n) return;

    const int s = lvl[nIdx];
    const float* __restrict__ Ws = &Wl[s * WPAD];
    const int*   __restrict__ ap = aprs + (size_t)nIdx * K;

    float acc0 = 0.f, acc1 = 0.f, acc2 = 0.f, acc3 = 0.f;

    #pragma unroll 3
    for (int k = 0; k < K; ++k) {
        const int nb = ap[k];
        const float4* __restrict__ xr =
            reinterpret_cast<const float4*>(x + (size_t)nb * CIN);
        // 64B row gather: 4x global_load_dwordx4
        const float4 v0 = xr[0];
        const float4 v1 = xr[1];
        const float4 v2 = xr[2];
        const float4 v3 = xr[3];

        const float* __restrict__ Wk = Ws + k * (CIN * COUT);

        float xv[16];
        xv[ 0] = v0.x; xv[ 1] = v0.y; xv[ 2] = v0.z; xv[ 3] = v0.w;
        xv[ 4] = v1.x; xv[ 5] = v1.y; xv[ 6] = v1.z; xv[ 7] = v1.w;
        xv[ 8] = v2.x; xv[ 9] = v2.y; xv[10] = v2.z; xv[11] = v2.w;
        xv[12] = v3.x; xv[13] = v3.y; xv[14] = v3.z; xv[15] = v3.w;

        #pragma unroll
        for (int c = 0; c < CIN; ++c) {
            // ds_read_b128 of W[s][k][c][0..3]; <=3 distinct addrs across wave
            const float4 w = *reinterpret_cast<const float4*>(&Wk[c * COUT]);
            acc0 = fmaf(xv[c], w.x, acc0);
            acc1 = fmaf(xv[c], w.y, acc1);
            acc2 = fmaf(xv[c], w.z, acc2);
            acc3 = fmaf(xv[c], w.w, acc3);
        }
    }

    float4 o;
    o.x = fmaxf(acc0, 0.f);
    o.y = fmaxf(acc1, 0.f);
    o.z = fmaxf(acc2, 0.f);
    o.w = fmaxf(acc3, 0.f);
    reinterpret_cast<float4*>(out)[nIdx] = o;
}

extern "C" void kernel_launch(void* const* d_in, const int* in_sizes, int n_in,
                              void* d_out, int out_size, void* d_ws, size_t ws_size,
                              hipStream_t stream) {
    const float* x    = (const float*)d_in[0];
    const float* W    = (const float*)d_in[1];
    const int*   aprs = (const int*)d_in[2];
    const int*   lvl  = (const int*)d_in[3];
    float*       out  = (float*)d_out;

    const int n = in_sizes[0] / CIN;   // N particles
    const int blocks = (n + 255) / 256;
    outblock_kernel<<<blocks, 256, 0, stream>>>(x, W, aprs, lvl, out, n);
}

// Round 3
// 686.005 us; speedup vs baseline: 1.0781x; 1.0781x over previous
//
#include <hip/hip_runtime.h>

// Problem constants (match reference)
constexpr int K    = 27;
constexpr int CIN  = 16;
constexpr int COUT = 4;
constexpr int NS   = 3;
constexpr int WSZ  = K * CIN * COUT;   // 1728 floats per stencil
// +8 floats pad per stencil: stride 1736 ≡ 8 (mod 32 banks) -> the 3 per-lane
// stencil variants hit disjoint bank groups on ds_read_b128.
constexpr int WPAD = WSZ + 8;

typedef unsigned int uint;
typedef float  f32x4 __attribute__((ext_vector_type(4)));   // native vec for nontemporal ops
typedef uint   u32x4 __attribute__((ext_vector_type(4)));

// ---- pass 1: x fp32 -> bf16 (RNE), packed 2 per dword ----
__device__ __forceinline__ uint bf16_rne(float f) {
    uint u = __float_as_uint(f);
    u += 0x7FFFu + ((u >> 16) & 1u);   // round to nearest even
    return u >> 16;
}

__global__ __launch_bounds__(256) void cvt_kernel(
    const float* __restrict__ x, uint* __restrict__ xh, int nvec)
{
    int i = blockIdx.x * 256 + threadIdx.x;
    if (i >= nvec) return;                 // nvec = N*CIN/8
    const f32x4* xf = reinterpret_cast<const f32x4*>(x) + 2 * (size_t)i;
    f32x4 a = __builtin_nontemporal_load(&xf[0]);
    f32x4 b = __builtin_nontemporal_load(&xf[1]);
    u32x4 o;
    o.x = bf16_rne(a.x) | (bf16_rne(a.y) << 16);
    o.y = bf16_rne(a.z) | (bf16_rne(a.w) << 16);
    o.z = bf16_rne(b.x) | (bf16_rne(b.y) << 16);
    o.w = bf16_rne(b.z) | (bf16_rne(b.w) << 16);
    __builtin_nontemporal_store(o, &reinterpret_cast<u32x4*>(xh)[i]);
}

__device__ __forceinline__ float blo(uint u) { return __uint_as_float(u << 16); }
__device__ __forceinline__ float bhi(uint u) { return __uint_as_float(u & 0xFFFF0000u); }

// ---- pass 2: gather bf16 rows + contraction ----
__global__ __launch_bounds__(256) void outblock_bf16(
    const uint*  __restrict__ xh,    // [N, 8] dwords (16 bf16)
    const float* __restrict__ W,     // [3, 27, 16, 4]
    const int*   __restrict__ aprs,  // [N, 27]
    const int*   __restrict__ lvl,   // [N]
    float*       __restrict__ out,   // [N, 4]
    int n)
{
    __shared__ float Wl[NS * WPAD];
    for (int i = threadIdx.x; i < NS * WSZ; i += 256) {
        int s = i / WSZ;
        Wl[s * WPAD + (i - s * WSZ)] = W[i];
    }
    __syncthreads();

    int nIdx = blockIdx.x * 256 + threadIdx.x;
    if (nIdx >= n) return;

    const int s = __builtin_nontemporal_load(&lvl[nIdx]);
    const float* __restrict__ Ws = &Wl[s * WPAD];
    const int*   __restrict__ ap = aprs + (size_t)nIdx * K;

    float acc0 = 0.f, acc1 = 0.f, acc2 = 0.f, acc3 = 0.f;

    #pragma unroll 3
    for (int k = 0; k < K; ++k) {
        const int nb = __builtin_nontemporal_load(&ap[k]);  // streamed once: keep out of L2
        const u32x4* __restrict__ xr =
            reinterpret_cast<const u32x4*>(xh + (size_t)nb * 8);
        const u32x4 p0 = xr[0];   // 32B row gather: 2x global_load_dwordx4
        const u32x4 p1 = xr[1];

        const float* __restrict__ Wk = Ws + k * (CIN * COUT);

        float xv[16];
        xv[ 0] = blo(p0.x); xv[ 1] = bhi(p0.x);
        xv[ 2] = blo(p0.y); xv[ 3] = bhi(p0.y);
        xv[ 4] = blo(p0.z); xv[ 5] = bhi(p0.z);
        xv[ 6] = blo(p0.w); xv[ 7] = bhi(p0.w);
        xv[ 8] = blo(p1.x); xv[ 9] = bhi(p1.x);
        xv[10] = blo(p1.y); xv[11] = bhi(p1.y);
        xv[12] = blo(p1.z); xv[13] = bhi(p1.z);
        xv[14] = blo(p1.w); xv[15] = bhi(p1.w);

        #pragma unroll
        for (int c = 0; c < CIN; ++c) {
            const float4 w = *reinterpret_cast<const float4*>(&Wk[c * COUT]);
            acc0 = fmaf(xv[c], w.x, acc0);
            acc1 = fmaf(xv[c], w.y, acc1);
            acc2 = fmaf(xv[c], w.z, acc2);
            acc3 = fmaf(xv[c], w.w, acc3);
        }
    }

    f32x4 o;
    o.x = fmaxf(acc0, 0.f);
    o.y = fmaxf(acc1, 0.f);
    o.z = fmaxf(acc2, 0.f);
    o.w = fmaxf(acc3, 0.f);
    __builtin_nontemporal_store(o, &reinterpret_cast<f32x4*>(out)[nIdx]);
}

// ---- fallback (fp32 gather, round-1 kernel) if ws too small ----
__global__ __launch_bounds__(256) void outblock_f32(
    const float* __restrict__ x,
    const float* __restrict__ W,
    const int*   __restrict__ aprs,
    const int*   __restrict__ lvl,
    float*       __restrict__ out,
    int n)
{
    __shared__ float Wl[NS * WPAD];
    for (int i = threadIdx.x; i < NS * WSZ; i += 256) {
        int s = i / WSZ;
        Wl[s * WPAD + (i - s * WSZ)] = W[i];
    }
    __syncthreads();

    int nIdx = blockIdx.x * 256 + threadIdx.x;
    if (nIdx >= n) return;

    const int s = lvl[nIdx];
    const float* __restrict__ Ws = &Wl[s * WPAD];
    const int*   __restrict__ ap = aprs + (size_t)nIdx * K;

    float acc0 = 0.f, acc1 = 0.f, acc2 = 0.f, acc3 = 0.f;

    #pragma unroll 3
    for (int k = 0; k < K; ++k) {
        const int nb = ap[k];
        const float4* __restrict__ xr =
            reinterpret_cast<const float4*>(x + (size_t)nb * CIN);
        const float4 v0 = xr[0];
        const float4 v1 = xr[1];
        const float4 v2 = xr[2];
        const float4 v3 = xr[3];

        const float* __restrict__ Wk = Ws + k * (CIN * COUT);
        float xv[16];
        xv[ 0] = v0.x; xv[ 1] = v0.y; xv[ 2] = v0.z; xv[ 3] = v0.w;
        xv[ 4] = v1.x; xv[ 5] = v1.y; xv[ 6] = v1.z; xv[ 7] = v1.w;
        xv[ 8] = v2.x; xv[ 9] = v2.y; xv[10] = v2.z; xv[11] = v2.w;
        xv[12] = v3.x; xv[13] = v3.y; xv[14] = v3.z; xv[15] = v3.w;

        #pragma unroll
        for (int c = 0; c < CIN; ++c) {
            const float4 w = *reinterpret_cast<const float4*>(&Wk[c * COUT]);
            acc0 = fmaf(xv[c], w.x, acc0);
            acc1 = fmaf(xv[c], w.y, acc1);
            acc2 = fmaf(xv[c], w.z, acc2);
            acc3 = fmaf(xv[c], w.w, acc3);
        }
    }

    float4 o;
    o.x = fmaxf(acc0, 0.f);
    o.y = fmaxf(acc1, 0.f);
    o.z = fmaxf(acc2, 0.f);
    o.w = fmaxf(acc3, 0.f);
    reinterpret_cast<float4*>(out)[nIdx] = o;
}

extern "C" void kernel_launch(void* const* d_in, const int* in_sizes, int n_in,
                              void* d_out, int out_size, void* d_ws, size_t ws_size,
                              hipStream_t stream) {
    const float* x    = (const float*)d_in[0];
    const float* W    = (const float*)d_in[1];
    const int*   aprs = (const int*)d_in[2];
    const int*   lvl  = (const int*)d_in[3];
    float*       out  = (float*)d_out;

    const int n = in_sizes[0] / CIN;               // N particles
    const size_t need = (size_t)n * CIN * 2;       // bf16 copy of x

    if (ws_size >= need) {
        uint* xh = (uint*)d_ws;
        const int nvec = n * CIN / 8;              // 8 floats per cvt thread
        cvt_kernel<<<(nvec + 255) / 256, 256, 0, stream>>>(x, xh, nvec);
        outblock_bf16<<<(n + 255) / 256, 256, 0, stream>>>(xh, W, aprs, lvl, out, n);
    } else {
        outblock_f32<<<(n + 255) / 256, 256, 0, stream>>>(x, W, aprs, lvl, out, n);
    }
}

// Round 4
// 490.437 us; speedup vs baseline: 1.5080x; 1.3988x over previous
//
#include <hip/hip_runtime.h>

// Problem constants (match reference)
constexpr int K    = 27;
constexpr int CIN  = 16;
constexpr int COUT = 4;
constexpr int NS   = 3;
constexpr int WSZ  = K * CIN * COUT;   // 1728 floats per stencil
constexpr int WPAD = WSZ + 8;          // bank-spread pad (see r1)

typedef unsigned int uint;
typedef float  f32x4 __attribute__((ext_vector_type(4)));
typedef uint   u32x4 __attribute__((ext_vector_type(4)));

// ---- pass 1: x fp32 -> bf16 (RNE), packed 2 per dword ----
__device__ __forceinline__ uint bf16_rne(float f) {
    uint u = __float_as_uint(f);
    u += 0x7FFFu + ((u >> 16) & 1u);
    return u >> 16;
}

__global__ __launch_bounds__(256) void cvt_kernel(
    const float* __restrict__ x, uint* __restrict__ xh, int nvec)
{
    int i = blockIdx.x * 256 + threadIdx.x;
    if (i >= nvec) return;                 // nvec = N*CIN/8
    const f32x4* xf = reinterpret_cast<const f32x4*>(x) + 2 * (size_t)i;
    f32x4 a = __builtin_nontemporal_load(&xf[0]);
    f32x4 b = __builtin_nontemporal_load(&xf[1]);
    u32x4 o;
    o.x = bf16_rne(a.x) | (bf16_rne(a.y) << 16);
    o.y = bf16_rne(a.z) | (bf16_rne(a.w) << 16);
    o.z = bf16_rne(b.x) | (bf16_rne(b.y) << 16);
    o.w = bf16_rne(b.z) | (bf16_rne(b.w) << 16);
    __builtin_nontemporal_store(o, &reinterpret_cast<u32x4*>(xh)[i]);
}

__device__ __forceinline__ float blo(uint u) { return __uint_as_float(u << 16); }
__device__ __forceinline__ float bhi(uint u) { return __uint_as_float(u & 0xFFFF0000u); }

// ---- gather-tile helpers: CNT rows staged in registers, static indexing ----
template<int CNT>
__device__ __forceinline__ void load_tile(
    const int* __restrict__ ap, int k0,
    const uint* __restrict__ xh, u32x4* __restrict__ r)
{
    #pragma unroll
    for (int g = 0; g < CNT; ++g) {
        const int nb = __builtin_nontemporal_load(&ap[k0 + g]);
        const u32x4* __restrict__ xr =
            reinterpret_cast<const u32x4*>(xh + (size_t)nb * 8);
        r[2 * g]     = xr[0];
        r[2 * g + 1] = xr[1];
    }
}

template<int CNT>
__device__ __forceinline__ void compute_tile(
    const float* __restrict__ Ws, int k0,
    const u32x4* __restrict__ r,
    float& a0, float& a1, float& a2, float& a3)
{
    #pragma unroll
    for (int g = 0; g < CNT; ++g) {
        const u32x4 p0 = r[2 * g];
        const u32x4 p1 = r[2 * g + 1];
        float xv[16];
        xv[ 0] = blo(p0.x); xv[ 1] = bhi(p0.x);
        xv[ 2] = blo(p0.y); xv[ 3] = bhi(p0.y);
        xv[ 4] = blo(p0.z); xv[ 5] = bhi(p0.z);
        xv[ 6] = blo(p0.w); xv[ 7] = bhi(p0.w);
        xv[ 8] = blo(p1.x); xv[ 9] = bhi(p1.x);
        xv[10] = blo(p1.y); xv[11] = bhi(p1.y);
        xv[12] = blo(p1.z); xv[13] = bhi(p1.z);
        xv[14] = blo(p1.w); xv[15] = bhi(p1.w);

        const float* __restrict__ Wk = Ws + (k0 + g) * (CIN * COUT);
        #pragma unroll
        for (int c = 0; c < CIN; ++c) {
            const float4 w = *reinterpret_cast<const float4*>(&Wk[c * COUT]);
            a0 = fmaf(xv[c], w.x, a0);
            a1 = fmaf(xv[c], w.y, a1);
            a2 = fmaf(xv[c], w.z, a2);
            a3 = fmaf(xv[c], w.w, a3);
        }
    }
}

// ---- pass 2: deep-pipelined gather + contraction ----
__global__ __launch_bounds__(256) void outblock_bf16(
    const uint*  __restrict__ xh,    // [N, 8] dwords (16 bf16)
    const float* __restrict__ W,     // [3, 27, 16, 4]
    const int*   __restrict__ aprs,  // [N, 27]
    const int*   __restrict__ lvl,   // [N]
    float*       __restrict__ out,   // [N, 4]
    int n)
{
    __shared__ float Wl[NS * WPAD];
    for (int i = threadIdx.x; i < NS * WSZ; i += 256) {
        int s = i / WSZ;
        Wl[s * WPAD + (i - s * WSZ)] = W[i];
    }
    __syncthreads();

    int nIdx = blockIdx.x * 256 + threadIdx.x;
    if (nIdx >= n) return;

    const int s = __builtin_nontemporal_load(&lvl[nIdx]);
    const float* __restrict__ Ws = &Wl[s * WPAD];
    const int*   __restrict__ ap = aprs + (size_t)nIdx * K;

    float a0 = 0.f, a1 = 0.f, a2 = 0.f, a3 = 0.f;

    // Double-buffered tiles of 7 rows: >=14 gather lines in flight sustained.
    u32x4 A[14], B[14];
    load_tile<7>(ap, 0,  xh, A);
    load_tile<7>(ap, 7,  xh, B);
    compute_tile<7>(Ws, 0,  A, a0, a1, a2, a3);
    load_tile<7>(ap, 14, xh, A);
    compute_tile<7>(Ws, 7,  B, a0, a1, a2, a3);
    load_tile<6>(ap, 21, xh, B);
    compute_tile<7>(Ws, 14, A, a0, a1, a2, a3);
    compute_tile<6>(Ws, 21, B, a0, a1, a2, a3);

    f32x4 o;
    o.x = fmaxf(a0, 0.f);
    o.y = fmaxf(a1, 0.f);
    o.z = fmaxf(a2, 0.f);
    o.w = fmaxf(a3, 0.f);
    __builtin_nontemporal_store(o, &reinterpret_cast<f32x4*>(out)[nIdx]);
}

// ---- fallback (fp32 gather) if ws too small ----
__global__ __launch_bounds__(256) void outblock_f32(
    const float* __restrict__ x,
    const float* __restrict__ W,
    const int*   __restrict__ aprs,
    const int*   __restrict__ lvl,
    float*       __restrict__ out,
    int n)
{
    __shared__ float Wl[NS * WPAD];
    for (int i = threadIdx.x; i < NS * WSZ; i += 256) {
        int s = i / WSZ;
        Wl[s * WPAD + (i - s * WSZ)] = W[i];
    }
    __syncthreads();

    int nIdx = blockIdx.x * 256 + threadIdx.x;
    if (nIdx >= n) return;

    const int s = lvl[nIdx];
    const float* __restrict__ Ws = &Wl[s * WPAD];
    const int*   __restrict__ ap = aprs + (size_t)nIdx * K;

    float acc0 = 0.f, acc1 = 0.f, acc2 = 0.f, acc3 = 0.f;

    #pragma unroll 3
    for (int k = 0; k < K; ++k) {
        const int nb = ap[k];
        const float4* __restrict__ xr =
            reinterpret_cast<const float4*>(x + (size_t)nb * CIN);
        const float4 v0 = xr[0];
        const float4 v1 = xr[1];
        const float4 v2 = xr[2];
        const float4 v3 = xr[3];

        const float* __restrict__ Wk = Ws + k * (CIN * COUT);
        float xv[16];
        xv[ 0] = v0.x; xv[ 1] = v0.y; xv[ 2] = v0.z; xv[ 3] = v0.w;
        xv[ 4] = v1.x; xv[ 5] = v1.y; xv[ 6] = v1.z; xv[ 7] = v1.w;
        xv[ 8] = v2.x; xv[ 9] = v2.y; xv[10] = v2.z; xv[11] = v2.w;
        xv[12] = v3.x; xv[13] = v3.y; xv[14] = v3.z; xv[15] = v3.w;

        #pragma unroll
        for (int c = 0; c < CIN; ++c) {
            const float4 w = *reinterpret_cast<const float4*>(&Wk[c * COUT]);
            acc0 = fmaf(xv[c], w.x, acc0);
            acc1 = fmaf(xv[c], w.y, acc1);
            acc2 = fmaf(xv[c], w.z, acc2);
            acc3 = fmaf(xv[c], w.w, acc3);
        }
    }

    float4 o;
    o.x = fmaxf(acc0, 0.f);
    o.y = fmaxf(acc1, 0.f);
    o.z = fmaxf(acc2, 0.f);
    o.w = fmaxf(acc3, 0.f);
    reinterpret_cast<float4*>(out)[nIdx] = o;
}

extern "C" void kernel_launch(void* const* d_in, const int* in_sizes, int n_in,
                              void* d_out, int out_size, void* d_ws, size_t ws_size,
                              hipStream_t stream) {
    const float* x    = (const float*)d_in[0];
    const float* W    = (const float*)d_in[1];
    const int*   aprs = (const int*)d_in[2];
    const int*   lvl  = (const int*)d_in[3];
    float*       out  = (float*)d_out;

    const int n = in_sizes[0] / CIN;               // N particles
    const size_t need = (size_t)n * CIN * 2;       // bf16 copy of x

    if (ws_size >= need) {
        uint* xh = (uint*)d_ws;
        const int nvec = n * CIN / 8;
        cvt_kernel<<<(nvec + 255) / 256, 256, 0, stream>>>(x, xh, nvec);
        outblock_bf16<<<(n + 255) / 256, 256, 0, stream>>>(xh, W, aprs, lvl, out, n);
    } else {
        outblock_f32<<<(n + 255) / 256, 256, 0, stream>>>(x, W, aprs, lvl, out, n);
    }
}